// Round 1
// baseline (7897.823 us; speedup 1.0000x reference)
//
#include <hip/hip_runtime.h>

#define NN 2048
#define NE 32768
#define DF 2048
#define TOPK 20
#define RMAXF 1e-5f
#define TMAX 48

// ---------------- init: adj=0, P=0, R=I, flags[0]=1 ----------------
__global__ __launch_bounds__(256) void init_kernel(float* __restrict__ adj, float* __restrict__ Ra,
                                                   float* __restrict__ P, int* __restrict__ flags) {
    int idx = blockIdx.x * 256 + threadIdx.x;
    if (idx < NN * NN) {
        adj[idx] = 0.0f;
        P[idx] = 0.0f;
        int r = idx >> 11, c = idx & (NN - 1);
        Ra[idx] = (r == c) ? 1.0f : 0.0f;
    }
    if (idx <= TMAX) flags[idx] = (idx == 0) ? 1 : 0;
}

// ---------------- scatter edges (duplicates summed) ----------------
__global__ __launch_bounds__(256) void edge_kernel(const int* __restrict__ ei, float* __restrict__ adj) {
    int e = blockIdx.x * 256 + threadIdx.x;
    if (e < NE) {
        int r = ei[e];
        int c = ei[NE + e];
        atomicAdd(&adj[(size_t)r * NN + c], 1.0f);
    }
}

// ---------------- row-normalize (deg==0 -> 1) ----------------
__global__ __launch_bounds__(256) void norm_kernel(float* __restrict__ adj) {
    __shared__ float red[256];
    int row = blockIdx.x, tid = threadIdx.x;
    float s = 0.0f;
    for (int j = tid; j < NN; j += 256) s += adj[(size_t)row * NN + j];
    red[tid] = s;
    __syncthreads();
    for (int st = 128; st > 0; st >>= 1) {
        if (tid < st) red[tid] += red[tid + st];
        __syncthreads();
    }
    float deg = red[0];
    if (deg == 0.0f) deg = 1.0f;
    for (int j = tid; j < NN; j += 256) adj[(size_t)row * NN + j] = adj[(size_t)row * NN + j] / deg;
}

// ---------------- one push round, fused:
//   push = (Rin >= RMAX) ? Rin : 0
//   Rout = (Rin - push) + 0.5 * push @ adj
//   P   += 0.5 * push
//   flags[t+1] = any(Rout >= RMAX)
// early-exits (exact no-op) when flags[t]==0.
__global__ __launch_bounds__(256) void iter_kernel(const float* __restrict__ Rin, float* __restrict__ Rout,
                                                   float* __restrict__ P, const float* __restrict__ adj,
                                                   int* __restrict__ flags, int t) {
    if (flags[t] == 0) return;   // uniform branch: converged, body is a no-op
    __shared__ float sA[16][68]; // [k][m], pad 68 (272B rows -> 16B-aligned float4, 2-way banks = free)
    __shared__ float sB[16][68]; // [k][n]
    int tid = threadIdx.x;
    int m0 = (blockIdx.x >> 5) << 6;
    int n0 = (blockIdx.x & 31) << 6;
    int tx = tid & 15, ty = tid >> 4;
    int lm = tid >> 2;         // 0..63  (A row within tile)
    int lk = (tid & 3) << 2;   // 0,4,8,12 (A k within tile)
    int bk = tid >> 4;         // 0..15 (B k within tile)
    int bn = (tid & 15) << 2;  // B col within tile

    float acc[4][4];
#pragma unroll
    for (int i = 0; i < 4; ++i)
#pragma unroll
        for (int j = 0; j < 4; ++j) acc[i][j] = 0.0f;

    for (int kk = 0; kk < NN; kk += 16) {
        float4 av = *(const float4*)&Rin[(size_t)(m0 + lm) * NN + kk + lk];
        av.x = (av.x >= RMAXF) ? av.x : 0.0f;
        av.y = (av.y >= RMAXF) ? av.y : 0.0f;
        av.z = (av.z >= RMAXF) ? av.z : 0.0f;
        av.w = (av.w >= RMAXF) ? av.w : 0.0f;
        float4 bv = *(const float4*)&adj[(size_t)(kk + bk) * NN + n0 + bn];
        sA[lk + 0][lm] = av.x;
        sA[lk + 1][lm] = av.y;
        sA[lk + 2][lm] = av.z;
        sA[lk + 3][lm] = av.w;
        sB[bk][bn + 0] = bv.x;
        sB[bk][bn + 1] = bv.y;
        sB[bk][bn + 2] = bv.z;
        sB[bk][bn + 3] = bv.w;
        __syncthreads();
#pragma unroll
        for (int k = 0; k < 16; ++k) {
            float4 a4 = *(const float4*)&sA[k][ty << 2];
            float4 b4 = *(const float4*)&sB[k][tx << 2];
            acc[0][0] += a4.x * b4.x; acc[0][1] += a4.x * b4.y; acc[0][2] += a4.x * b4.z; acc[0][3] += a4.x * b4.w;
            acc[1][0] += a4.y * b4.x; acc[1][1] += a4.y * b4.y; acc[1][2] += a4.y * b4.z; acc[1][3] += a4.y * b4.w;
            acc[2][0] += a4.z * b4.x; acc[2][1] += a4.z * b4.y; acc[2][2] += a4.z * b4.z; acc[2][3] += a4.z * b4.w;
            acc[3][0] += a4.w * b4.x; acc[3][1] += a4.w * b4.y; acc[3][2] += a4.w * b4.z; acc[3][3] += a4.w * b4.w;
        }
        __syncthreads();
    }

    bool anyAbove = false;
#pragma unroll
    for (int i = 0; i < 4; ++i) {
        int gi = m0 + (ty << 2) + i;
#pragma unroll
        for (int j = 0; j < 4; ++j) {
            int gj = n0 + (tx << 2) + j;
            size_t off = (size_t)gi * NN + gj;
            float r = Rin[off];
            float push = (r >= RMAXF) ? r : 0.0f;
            float ro = (r - push) + 0.5f * acc[i][j];
            Rout[off] = ro;
            if (push > 0.0f) P[off] += 0.5f * push;
            anyAbove |= (ro >= RMAXF);
        }
    }
    // racy-but-idempotent: many waves store 1; init was 0; read next kernel
    if (__ballot(anyAbove) != 0ULL) {
        if ((tid & 63) == 0) flags[t + 1] = 1;
    }
}

// ---------------- top-20 per row (lowest-index tie-break, matches lax.top_k) ----------------
__global__ __launch_bounds__(256) void topk_kernel(const float* __restrict__ P, float* __restrict__ tkv,
                                                   int* __restrict__ tki) {
    __shared__ float sv[NN];
    __shared__ float cv[256];
    __shared__ int ci[256];
    int row = blockIdx.x, tid = threadIdx.x;
    for (int j = tid; j < NN; j += 256) sv[j] = P[(size_t)row * NN + j];
    __syncthreads();
    for (int s = 0; s < TOPK; ++s) {
        float bv = -1.0f;
        int bi = 0;
        int base = tid * 8;  // blocked ownership -> cross-thread idx order == tid order
#pragma unroll
        for (int j = 0; j < 8; ++j) {
            float v = sv[base + j];
            if (v > bv) { bv = v; bi = base + j; }  // strict > keeps lowest index
        }
        cv[tid] = bv; ci[tid] = bi;
        __syncthreads();
        for (int st = 128; st > 0; st >>= 1) {
            if (tid < st) {
                float ov = cv[tid + st]; int oi = ci[tid + st];
                if (ov > cv[tid] || (ov == cv[tid] && oi < ci[tid])) { cv[tid] = ov; ci[tid] = oi; }
            }
            __syncthreads();
        }
        if (tid == 0) {
            tkv[row * TOPK + s] = cv[0];
            tki[row * TOPK + s] = ci[0];
            sv[ci[0]] = -1.0f;  // P >= 0, so -1 is a safe sentinel
        }
        __syncthreads();
    }
}

// ---------------- out[row] = sum_v w_v * feats[idx_v]  (overwrites P in d_out) ----------------
__global__ __launch_bounds__(256) void final_kernel(const float* __restrict__ feats, const float* __restrict__ tkv,
                                                    const int* __restrict__ tki, float* __restrict__ out) {
    __shared__ float wv[TOPK];
    __shared__ int wi[TOPK];
    int row = blockIdx.x, tid = threadIdx.x;
    if (tid < TOPK) {
        wv[tid] = tkv[row * TOPK + tid];
        wi[tid] = tki[row * TOPK + tid];
    }
    __syncthreads();
    int c0 = tid * 8;
    float4 a0 = {0, 0, 0, 0}, a1 = {0, 0, 0, 0};
    for (int v = 0; v < TOPK; ++v) {
        float w = wv[v];
        int id = wi[v];
        const float4* fr = (const float4*)&feats[(size_t)id * DF + c0];
        float4 f0 = fr[0], f1 = fr[1];
        a0.x += w * f0.x; a0.y += w * f0.y; a0.z += w * f0.z; a0.w += w * f0.w;
        a1.x += w * f1.x; a1.y += w * f1.y; a1.z += w * f1.z; a1.w += w * f1.w;
    }
    float4* op = (float4*)&out[(size_t)row * DF + c0];
    op[0] = a0;
    op[1] = a1;
}

extern "C" void kernel_launch(void* const* d_in, const int* in_sizes, int n_in,
                              void* d_out, int out_size, void* d_ws, size_t ws_size,
                              hipStream_t stream) {
    const float* feats = (const float*)d_in[0];
    const int* ei = (const int*)d_in[1];
    float* out = (float*)d_out;  // doubles as P during iterations

    float* adj = (float*)d_ws;           // 16 MB
    float* Ra = adj + (size_t)NN * NN;   // 16 MB
    float* Rb = Ra + (size_t)NN * NN;    // 16 MB
    float* tkv = Rb + (size_t)NN * NN;   // 2048*20 floats
    int* tki = (int*)(tkv + NN * TOPK);  // 2048*20 ints
    int* flags = tki + NN * TOPK;        // TMAX+1 ints

    init_kernel<<<(NN * NN + 255) / 256, 256, 0, stream>>>(adj, Ra, out, flags);
    edge_kernel<<<(NE + 255) / 256, 256, 0, stream>>>(ei, adj);
    norm_kernel<<<NN, 256, 0, stream>>>(adj);

    float* rin = Ra;
    float* rout = Rb;
    for (int t = 0; t < TMAX; ++t) {
        iter_kernel<<<dim3(1024), 256, 0, stream>>>(rin, rout, out, adj, flags, t);
        float* tmp = rin; rin = rout; rout = tmp;
    }

    topk_kernel<<<NN, 256, 0, stream>>>(out, tkv, tki);
    final_kernel<<<NN, 256, 0, stream>>>(feats, tkv, tki, out);
}

// Round 5
// 1649.686 us; speedup vs baseline: 4.7875x; 4.7875x over previous
//
#include <hip/hip_runtime.h>

#define NN 2048
#define NE 32768
#define DF 2048
#define TOPK 20
#define RMAXF 1e-5f

typedef __attribute__((ext_vector_type(4))) float f32x4;

// ---------------- zero counts/cursor ----------------
__global__ __launch_bounds__(256) void zero_kernel(int* __restrict__ counts, int* __restrict__ cursor) {
    int idx = blockIdx.x * 256 + threadIdx.x;
    if (idx < NN) { counts[idx] = 0; cursor[idx] = 0; }
}

// ---------------- per-row edge counts (duplicates kept) ----------------
__global__ __launch_bounds__(256) void count_kernel(const int* __restrict__ ei, int* __restrict__ counts) {
    int e = blockIdx.x * 256 + threadIdx.x;
    if (e < NE) atomicAdd(&counts[ei[e]], 1);
}

// ---------------- exclusive scan -> rowptr; winv05 = 0.5/deg ----------------
__global__ __launch_bounds__(256) void scan_kernel(const int* __restrict__ counts, int* __restrict__ rowptr,
                                                   float* __restrict__ winv05) {
    __shared__ int part[256];
    int tid = threadIdx.x;
    int base = tid * 8;
    int loc[8];
    int s = 0;
#pragma unroll
    for (int l = 0; l < 8; ++l) { loc[l] = s; s += counts[base + l]; }
    part[tid] = s;
    __syncthreads();
    for (int off = 1; off < 256; off <<= 1) {
        int v = (tid >= off) ? part[tid - off] : 0;
        __syncthreads();
        part[tid] += v;
        __syncthreads();
    }
    int excl = part[tid] - s;  // exclusive prefix of this thread's block
#pragma unroll
    for (int l = 0; l < 8; ++l) {
        rowptr[base + l] = excl + loc[l];
        int c = counts[base + l];
        winv05[base + l] = c ? 0.5f / (float)c : 0.0f;  // deg==0 row spreads nothing (adj row all zero)
    }
    if (tid == 255) rowptr[NN] = excl + s;
}

// ---------------- fill CSR cols (order within row arbitrary; weights uniform per row) ----------------
__global__ __launch_bounds__(256) void fill_kernel(const int* __restrict__ ei, const int* __restrict__ rowptr,
                                                   int* __restrict__ cursor, int* __restrict__ cols) {
    int e = blockIdx.x * 256 + threadIdx.x;
    if (e < NE) {
        int r = ei[e];
        int c = ei[NE + e];
        int pos = atomicAdd(&cursor[r], 1);
        cols[rowptr[r] + pos] = c;
    }
}

// ---------------- per-source-row local push + top-20, all in LDS ----------------
// Row decoupling: Rout[i] depends only on Rin[i]; converged rows are exact no-ops,
// so per-row independent iteration yields bit-identical P to the global while_loop.
__global__ __launch_bounds__(256) void push_topk_kernel(const int* __restrict__ rowptr_g,
                                                        const int* __restrict__ cols,
                                                        const float* __restrict__ winv05,
                                                        float* __restrict__ tkv, int* __restrict__ tki) {
    __shared__ float R[NN];
    __shared__ float D[NN];   // incoming spread; reused as cv/ci scratch for topk
    __shared__ float P[NN];
    __shared__ int srp[NN + 1];
    __shared__ int sflag;

    int row = blockIdx.x, tid = threadIdx.x;
    int base = tid * 8;

#pragma unroll
    for (int l = 0; l < 8; ++l) {
        int j = base + l;
        R[j] = 0.0f;
        D[j] = 0.0f;
        P[j] = 0.0f;
        srp[j] = rowptr_g[j];
    }
    if (tid == 0) { srp[NN] = rowptr_g[NN]; sflag = 0; }
    __syncthreads();
    if (tid == 0) R[row] = 1.0f;  // R = e_row
    __syncthreads();

    int flagreg = 1;  // any(R >= RMAX) is true initially (R[row]=1)
    while (flagreg) {
        // ---- phase A: push owned entries >= RMAX; accumulate P; scatter spread into D ----
#pragma unroll
        for (int l = 0; l < 8; ++l) {
            int j = base + l;
            float r = R[j];
            if (r >= RMAXF) {
                P[j] += 0.5f * r;
                float amt = r * winv05[j];  // 0.5 * push / deg_j
                int b = srp[j], en = srp[j + 1];
                for (int p = b; p < en; ++p) atomicAdd(&D[cols[p]], amt);
            }
        }
        __syncthreads();
        if (tid == 0) sflag = 0;
        __syncthreads();
        // ---- phase B: synchronous update R = R - push + D; D = 0; next-round flag ----
        bool above = false;
#pragma unroll
        for (int l = 0; l < 8; l += 4) {
            int j = base + l;
            f32x4 r4 = *(f32x4*)&R[j];
            f32x4 d4 = *(f32x4*)&D[j];
            f32x4 rn;
#pragma unroll
            for (int u = 0; u < 4; ++u) {
                float r = r4[u];
                float push = (r >= RMAXF) ? r : 0.0f;
                float v = (r - push) + d4[u];
                rn[u] = v;
                above |= (v >= RMAXF);
            }
            *(f32x4*)&R[j] = rn;
            *(f32x4*)&D[j] = (f32x4){0.f, 0.f, 0.f, 0.f};
        }
        if (above) sflag = 1;  // racy 1-stores, benign
        __syncthreads();
        flagreg = sflag;
    }

    // ---- top-20 of P (lowest-index tie-break, matches lax.top_k stable order) ----
    float* cv = (float*)D;        // D is dead; reuse
    int* ci = (int*)(D + 256);
    for (int s = 0; s < TOPK; ++s) {
        float bv = -1.0f;
        int bi = 0;
#pragma unroll
        for (int l = 0; l < 8; ++l) {
            float v = P[base + l];
            if (v > bv) { bv = v; bi = base + l; }  // strict > keeps lowest index
        }
        cv[tid] = bv;
        ci[tid] = bi;
        __syncthreads();
        for (int st = 128; st > 0; st >>= 1) {
            if (tid < st) {
                float ov = cv[tid + st];
                int oi = ci[tid + st];
                if (ov > cv[tid] || (ov == cv[tid] && oi < ci[tid])) { cv[tid] = ov; ci[tid] = oi; }
            }
            __syncthreads();
        }
        if (tid == 0) {
            tkv[row * TOPK + s] = cv[0];
            tki[row * TOPK + s] = ci[0];
            P[ci[0]] = -1.0f;  // P >= 0, safe sentinel
        }
        __syncthreads();
    }
}

// ---------------- out[row] = sum_v w_v * feats[idx_v] ----------------
__global__ __launch_bounds__(256) void final_kernel(const float* __restrict__ feats, const float* __restrict__ tkv,
                                                    const int* __restrict__ tki, float* __restrict__ out) {
    __shared__ float wv[TOPK];
    __shared__ int wi[TOPK];
    int row = blockIdx.x, tid = threadIdx.x;
    if (tid < TOPK) {
        wv[tid] = tkv[row * TOPK + tid];
        wi[tid] = tki[row * TOPK + tid];
    }
    __syncthreads();
    int c0 = tid * 8;
    float4 a0 = {0, 0, 0, 0}, a1 = {0, 0, 0, 0};
    for (int v = 0; v < TOPK; ++v) {
        float w = wv[v];
        int id = wi[v];
        const float4* fr = (const float4*)&feats[(size_t)id * DF + c0];
        float4 g0 = fr[0], g1 = fr[1];
        a0.x += w * g0.x; a0.y += w * g0.y; a0.z += w * g0.z; a0.w += w * g0.w;
        a1.x += w * g1.x; a1.y += w * g1.y; a1.z += w * g1.z; a1.w += w * g1.w;
    }
    float4* op = (float4*)&out[(size_t)row * DF + c0];
    op[0] = a0;
    op[1] = a1;
}

extern "C" void kernel_launch(void* const* d_in, const int* in_sizes, int n_in,
                              void* d_out, int out_size, void* d_ws, size_t ws_size,
                              hipStream_t stream) {
    const float* feats = (const float*)d_in[0];
    const int* ei = (const int*)d_in[1];
    float* out = (float*)d_out;

    int* counts = (int*)d_ws;                 // 2048
    int* cursor = counts + NN;                // 2048
    int* rowptr = cursor + NN;                // 2049 (+pad)
    float* winv05 = (float*)(rowptr + NN + 4);// 2048
    int* cols = (int*)(winv05 + NN);          // 32768
    float* tkv = (float*)(cols + NE);         // 2048*20
    int* tki = (int*)(tkv + NN * TOPK);       // 2048*20

    zero_kernel<<<(NN + 255) / 256, 256, 0, stream>>>(counts, cursor);
    count_kernel<<<(NE + 255) / 256, 256, 0, stream>>>(ei, counts);
    scan_kernel<<<1, 256, 0, stream>>>(counts, rowptr, winv05);
    fill_kernel<<<(NE + 255) / 256, 256, 0, stream>>>(ei, rowptr, cursor, cols);
    push_topk_kernel<<<NN, 256, 0, stream>>>(rowptr, cols, winv05, tkv, tki);
    final_kernel<<<NN, 256, 0, stream>>>(feats, tkv, tki, out);
}